// Round 1
// baseline (1255.146 us; speedup 1.0000x reference)
//
#include <hip/hip_runtime.h>

#define N_NODES 100000
#define N_EDGES 1600000
#define D 128

// ---------------- CSR build ----------------

__global__ void hist_kernel(const int* __restrict__ dst, int* __restrict__ deg, int n) {
    int i = blockIdx.x * blockDim.x + threadIdx.x;
    if (i < n) atomicAdd(&deg[dst[i]], 1);
}

__global__ __launch_bounds__(1024) void scan_kernel(const int* __restrict__ deg,
                                                    int* __restrict__ off, int n) {
    __shared__ int sums[1024];
    int tid = threadIdx.x;
    int per = (n + 1023) >> 10;
    int start = tid * per;
    int end = start + per;
    if (start > n) start = n;
    if (end > n) end = n;
    int s = 0;
    for (int i = start; i < end; i++) s += deg[i];
    sums[tid] = s;
    __syncthreads();
    // Hillis-Steele inclusive scan over 1024 partials
    for (int d = 1; d < 1024; d <<= 1) {
        int v = (tid >= d) ? sums[tid - d] : 0;
        __syncthreads();
        sums[tid] += v;
        __syncthreads();
    }
    int prefix = (tid == 0) ? 0 : sums[tid - 1];
    for (int i = start; i < end; i++) { off[i] = prefix; prefix += deg[i]; }
    if (tid == 0) off[n] = sums[1023];
}

__global__ void scatter_kernel(const int* __restrict__ srcv, const int* __restrict__ dstv,
                               const int* __restrict__ off, int* __restrict__ cnt,
                               int* __restrict__ csr, int n) {
    int i = blockIdx.x * blockDim.x + threadIdx.x;
    if (i < n) {
        int d = dstv[i];
        int p = off[d] + atomicAdd(&cnt[d], 1);
        csr[p] = srcv[i];
    }
}

// ---------------- aggregation: t[i] = x[i] + sum_{j in N_in(i)} x[j] ----------------

__global__ __launch_bounds__(128) void agg_kernel(const float* __restrict__ x,
                                                  const int* __restrict__ off,
                                                  const int* __restrict__ csr,
                                                  float* __restrict__ t) {
    int i = blockIdx.x;
    int j = threadIdx.x;
    float acc = x[(size_t)i * D + j];
    int s = off[i], e = off[i + 1];
    for (int k = s; k < e; k++) {
        int nb = csr[k];                 // uniform across block -> scalar load
        acc += x[(size_t)nb * D + j];    // 512B coalesced gather
    }
    t[(size_t)i * D + j] = acc;
}

// ---------------- GEMM: out = relu(A @ W + bias), A: M x 128, W: 128 x 128 ----------------
// 128x128 output tile per block, 256 threads, 8x8 register tile per thread.
// In-place safe: each block reads only the A-rows it writes, all loads precede the store.

__global__ __launch_bounds__(256) void gemm_bias_relu(const float* __restrict__ A,
                                                      const float* __restrict__ W,
                                                      const float* __restrict__ bias,
                                                      float* __restrict__ out, int M) {
    __shared__ float As[32][128];   // As[k][m] (transposed for contiguous fragment reads)
    __shared__ float Bs[32][128];   // Bs[k][n]
    int tid = threadIdx.x;
    int ty = tid >> 4;              // 0..15 row group
    int tx = tid & 15;              // 0..15 col group
    int m0 = blockIdx.x * 128;

    float acc[8][8];
#pragma unroll
    for (int i = 0; i < 8; i++)
#pragma unroll
        for (int j = 0; j < 8; j++) acc[i][j] = 0.0f;

    for (int k0 = 0; k0 < 128; k0 += 32) {
#pragma unroll
        for (int i = 0; i < 4; i++) {
            int linear = tid + i * 256;          // 0..1023
            // A chunk: 128 rows x 32 cols = 1024 float4
            int arow = linear >> 3;
            int ac = (linear & 7) << 2;
            int m = m0 + arow;
            if (m >= M) m = M - 1;
            const float4 av = *(const float4*)(A + (size_t)m * D + k0 + ac);
            As[ac + 0][arow] = av.x;
            As[ac + 1][arow] = av.y;
            As[ac + 2][arow] = av.z;
            As[ac + 3][arow] = av.w;
            // W chunk: 32 rows x 128 cols = 1024 float4
            int wrow = linear >> 5;
            int wc = (linear & 31) << 2;
            *(float4*)&Bs[wrow][wc] = *(const float4*)(W + (size_t)(k0 + wrow) * D + wc);
        }
        __syncthreads();
#pragma unroll
        for (int k = 0; k < 32; k++) {
            float4 a0 = *(const float4*)&As[k][ty * 8];
            float4 a1 = *(const float4*)&As[k][ty * 8 + 4];
            float4 b0 = *(const float4*)&Bs[k][tx * 8];
            float4 b1 = *(const float4*)&Bs[k][tx * 8 + 4];
            float a[8] = {a0.x, a0.y, a0.z, a0.w, a1.x, a1.y, a1.z, a1.w};
            float b[8] = {b0.x, b0.y, b0.z, b0.w, b1.x, b1.y, b1.z, b1.w};
#pragma unroll
            for (int i = 0; i < 8; i++)
#pragma unroll
                for (int j = 0; j < 8; j++) acc[i][j] = fmaf(a[i], b[j], acc[i][j]);
        }
        __syncthreads();
    }

#pragma unroll
    for (int i = 0; i < 8; i++) {
        int m = m0 + ty * 8 + i;
        if (m < M) {
#pragma unroll
            for (int j = 0; j < 8; j += 4) {
                int n = tx * 8 + j;
                float4 o;
                o.x = fmaxf(acc[i][j + 0] + bias[n + 0], 0.0f);
                o.y = fmaxf(acc[i][j + 1] + bias[n + 1], 0.0f);
                o.z = fmaxf(acc[i][j + 2] + bias[n + 2], 0.0f);
                o.w = fmaxf(acc[i][j + 3] + bias[n + 3], 0.0f);
                *(float4*)(out + (size_t)m * D + n) = o;
            }
        }
    }
}

// ---------------- launch ----------------

extern "C" void kernel_launch(void* const* d_in, const int* in_sizes, int n_in,
                              void* d_out, int out_size, void* d_ws, size_t ws_size,
                              hipStream_t stream) {
    const float* x = (const float*)d_in[0];
    const int* ei = (const int*)d_in[1];
    const int* srcv = ei;
    const int* dstv = ei + N_EDGES;
    const float* W1[3] = {(const float*)d_in[2], (const float*)d_in[6], (const float*)d_in[10]};
    const float* b1[3] = {(const float*)d_in[3], (const float*)d_in[7], (const float*)d_in[11]};
    const float* W2[3] = {(const float*)d_in[4], (const float*)d_in[8], (const float*)d_in[12]};
    const float* b2[3] = {(const float*)d_in[5], (const float*)d_in[9], (const float*)d_in[13]};
    float* outp = (float*)d_out;

    char* ws = (char*)d_ws;
    int* off = (int*)ws;                               // (N+1) ints
    int* cnt = (int*)(ws + 400128);                    // N ints (deg, then cursor)
    int* csr = (int*)(ws + 800256);                    // E ints
    float* bufA = (float*)(ws + 7200256);              // N*D floats

    // --- CSR build (once; reused by all 3 layers) ---
    hipMemsetAsync(cnt, 0, (size_t)N_NODES * 4, stream);
    hist_kernel<<<(N_EDGES + 255) / 256, 256, 0, stream>>>(dstv, cnt, N_EDGES);
    scan_kernel<<<1, 1024, 0, stream>>>(cnt, off, N_NODES);
    hipMemsetAsync(cnt, 0, (size_t)N_NODES * 4, stream);
    scatter_kernel<<<(N_EDGES + 255) / 256, 256, 0, stream>>>(srcv, dstv, off, cnt, csr, N_EDGES);

    const int gemm_grid = (N_NODES + 127) / 128;
    float* P = bufA;
    float* Q = outp;

    // layer 0: x_in = d_in[0]
    agg_kernel<<<N_NODES, 128, 0, stream>>>(x, off, csr, P);                       // t -> P
    gemm_bias_relu<<<gemm_grid, 256, 0, stream>>>(P, W1[0], b1[0], Q, N_NODES);    // u -> Q
    gemm_bias_relu<<<gemm_grid, 256, 0, stream>>>(Q, W2[0], b2[0], P, N_NODES);    // x1 -> P

    // layer 1
    agg_kernel<<<N_NODES, 128, 0, stream>>>(P, off, csr, Q);                       // t -> Q
    gemm_bias_relu<<<gemm_grid, 256, 0, stream>>>(Q, W1[1], b1[1], P, N_NODES);    // u -> P
    gemm_bias_relu<<<gemm_grid, 256, 0, stream>>>(P, W2[1], b2[1], Q, N_NODES);    // x2 -> Q

    // layer 2
    agg_kernel<<<N_NODES, 128, 0, stream>>>(Q, off, csr, P);                       // t -> P
    gemm_bias_relu<<<gemm_grid, 256, 0, stream>>>(P, W1[2], b1[2], Q, N_NODES);    // u -> Q
    gemm_bias_relu<<<gemm_grid, 256, 0, stream>>>(Q, W2[2], b2[2], Q, N_NODES);    // out (in-place safe)
}

// Round 2
// 832.612 us; speedup vs baseline: 1.5075x; 1.5075x over previous
//
#include <hip/hip_runtime.h>

#define N_NODES 100000
#define N_EDGES 1600000
#define D 128

typedef __attribute__((ext_vector_type(8))) short bf16x8;
typedef __attribute__((ext_vector_type(4))) float f32x4;

__device__ __forceinline__ float b2f_lo(unsigned int u) {
    return __builtin_bit_cast(float, u << 16);
}
__device__ __forceinline__ float b2f_hi(unsigned int u) {
    return __builtin_bit_cast(float, u & 0xFFFF0000u);
}
__device__ __forceinline__ unsigned short f2b(float f) {
    unsigned int u = __builtin_bit_cast(unsigned int, f);
    u += 0x7FFFu + ((u >> 16) & 1u);
    return (unsigned short)(u >> 16);
}

// ---------------- CSR build ----------------

__global__ void hist_kernel(const int* __restrict__ dst, int* __restrict__ deg, int n) {
    int i = blockIdx.x * blockDim.x + threadIdx.x;
    if (i < n) atomicAdd(&deg[dst[i]], 1);
}

__global__ __launch_bounds__(1024) void scan_kernel(const int* __restrict__ deg,
                                                    int* __restrict__ off, int n) {
    __shared__ int sums[1024];
    int tid = threadIdx.x;
    int per = (n + 1023) >> 10;
    int start = tid * per;
    int end = start + per;
    if (start > n) start = n;
    if (end > n) end = n;
    int s = 0;
    for (int i = start; i < end; i++) s += deg[i];
    sums[tid] = s;
    __syncthreads();
    for (int d = 1; d < 1024; d <<= 1) {
        int v = (tid >= d) ? sums[tid - d] : 0;
        __syncthreads();
        sums[tid] += v;
        __syncthreads();
    }
    int prefix = (tid == 0) ? 0 : sums[tid - 1];
    for (int i = start; i < end; i++) { off[i] = prefix; prefix += deg[i]; }
    if (tid == 0) off[n] = sums[1023];
}

__global__ void scatter_kernel(const int* __restrict__ srcv, const int* __restrict__ dstv,
                               const int* __restrict__ off, int* __restrict__ cnt,
                               int* __restrict__ csr, int n) {
    int i = blockIdx.x * blockDim.x + threadIdx.x;
    if (i < n) {
        int d = dstv[i];
        int p = off[d] + atomicAdd(&cnt[d], 1);
        csr[p] = srcv[i];
    }
}

// ---------------- dtype conversion ----------------

__global__ __launch_bounds__(256) void convert_x_kernel(const float* __restrict__ x,
                                                        unsigned short* __restrict__ xb, int n4) {
    int i = blockIdx.x * 256 + threadIdx.x;
    if (i < n4) {
        float4 v = ((const float4*)x)[i];
        ushort4 o;
        o.x = f2b(v.x); o.y = f2b(v.y); o.z = f2b(v.z); o.w = f2b(v.w);
        ((ushort4*)xb)[i] = o;
    }
}

// W: [k][n] fp32 -> Wt: [n][k] bf16, 6 weights in one launch (blockIdx.y selects)
__global__ __launch_bounds__(256) void convert_w6_kernel(
    const float* __restrict__ W0, const float* __restrict__ W1_, const float* __restrict__ W2_,
    const float* __restrict__ W3, const float* __restrict__ W4, const float* __restrict__ W5,
    unsigned short* __restrict__ T0, unsigned short* __restrict__ T1_,
    unsigned short* __restrict__ T2_, unsigned short* __restrict__ T3,
    unsigned short* __restrict__ T4, unsigned short* __restrict__ T5) {
    const float* W;
    unsigned short* T;
    switch (blockIdx.y) {
        case 0: W = W0; T = T0; break;
        case 1: W = W1_; T = T1_; break;
        case 2: W = W2_; T = T2_; break;
        case 3: W = W3; T = T3; break;
        case 4: W = W4; T = T4; break;
        default: W = W5; T = T5; break;
    }
    int i = blockIdx.x * 256 + threadIdx.x;   // 0..16383
    int k = i >> 7, n = i & 127;
    T[n * 128 + k] = f2b(W[i]);
}

// ---------------- aggregation: t[i] = x[i] + sum_{j in N_in(i)} x[j]  (bf16 in/out) ----------------
// 4 waves per block, one node per wave; each lane handles 2 features (one dword).

__global__ __launch_bounds__(256) void agg_bf16(const unsigned int* __restrict__ xb,
                                                const int* __restrict__ off,
                                                const int* __restrict__ csr,
                                                unsigned int* __restrict__ t) {
    int node = blockIdx.x * 4 + (threadIdx.x >> 6);
    if (node >= N_NODES) return;
    int lane = threadIdx.x & 63;
    unsigned int v = xb[(size_t)node * 64 + lane];
    float ax = b2f_lo(v), ay = b2f_hi(v);
    int e = off[node + 1];
    int k = off[node];
    for (; k + 4 <= e; k += 4) {
        int n0 = csr[k + 0], n1 = csr[k + 1], n2 = csr[k + 2], n3 = csr[k + 3];
        unsigned int g0 = xb[(size_t)n0 * 64 + lane];
        unsigned int g1 = xb[(size_t)n1 * 64 + lane];
        unsigned int g2 = xb[(size_t)n2 * 64 + lane];
        unsigned int g3 = xb[(size_t)n3 * 64 + lane];
        ax += b2f_lo(g0) + b2f_lo(g1) + b2f_lo(g2) + b2f_lo(g3);
        ay += b2f_hi(g0) + b2f_hi(g1) + b2f_hi(g2) + b2f_hi(g3);
    }
    for (; k < e; k++) {
        unsigned int g = xb[(size_t)csr[k] * 64 + lane];
        ax += b2f_lo(g);
        ay += b2f_hi(g);
    }
    t[(size_t)node * 64 + lane] = (unsigned int)f2b(ax) | ((unsigned int)f2b(ay) << 16);
}

// ---------------- GEMM: out = relu(A @ W + bias) via bf16 MFMA ----------------
// A: M x 128 bf16. Wt: 128x128 bf16 pre-transposed [n][k] (B^T layout). 256 thr = 4 waves,
// 64 rows per block (16 per wave). A/B frags direct from global (Wt is L2-resident).
// Epilogue stages per-wave 16x128 tile in LDS for coalesced stores (no barriers needed).

template <bool OUT_F32>
__global__ __launch_bounds__(256) void gemm_mfma(const unsigned short* __restrict__ A,
                                                 const unsigned short* __restrict__ Wt,
                                                 const float* __restrict__ bias,
                                                 void* __restrict__ out, int M) {
    __shared__ char smem[4][8448];  // per-wave staging: 16 rows x (132 f32 | 136 bf16)
    int tid = threadIdx.x;
    int wave = tid >> 6, lane = tid & 63;
    int quad = lane >> 4, mr = lane & 15;
    int m_base = blockIdx.x * 64 + wave * 16;
    int m = m_base + mr;
    if (m >= M) m = M - 1;

    bf16x8 a[4];
#pragma unroll
    for (int kc = 0; kc < 4; kc++)
        a[kc] = *(const bf16x8*)(A + (size_t)m * D + kc * 32 + quad * 8);

    f32x4 acc[8];
#pragma unroll
    for (int nt = 0; nt < 8; nt++) acc[nt] = (f32x4)0.0f;

#pragma unroll
    for (int nt = 0; nt < 8; nt++) {
        const unsigned short* wp = Wt + (size_t)(nt * 16 + mr) * D + quad * 8;
#pragma unroll
        for (int kc = 0; kc < 4; kc++) {
            bf16x8 b = *(const bf16x8*)(wp + kc * 32);
            acc[nt] = __builtin_amdgcn_mfma_f32_16x16x32_bf16(a[kc], b, acc[nt], 0, 0, 0);
        }
    }

    // D layout: col = lane&15 (=mr), row = quad*4 + reg
    if (OUT_F32) {
        float* st = (float*)smem[wave];
        const int S = 132;
#pragma unroll
        for (int nt = 0; nt < 8; nt++) {
            float bv = bias[nt * 16 + mr];
#pragma unroll
            for (int r = 0; r < 4; r++)
                st[(quad * 4 + r) * S + nt * 16 + mr] = fmaxf(acc[nt][r] + bv, 0.0f);
        }
        float* op = (float*)out;
#pragma unroll
        for (int it = 0; it < 8; it++) {
            int linear = lane + it * 64;        // 512 float4-chunks: 16 rows x 32
            int row = linear >> 5, col = (linear & 31) << 2;
            int gm = m_base + row;
            if (gm < M) {
                float4 val = *(float4*)&st[row * S + col];
                *(float4*)(op + (size_t)gm * D + col) = val;
            }
        }
    } else {
        unsigned short* st = (unsigned short*)smem[wave];
        const int S = 136;
#pragma unroll
        for (int nt = 0; nt < 8; nt++) {
            float bv = bias[nt * 16 + mr];
#pragma unroll
            for (int r = 0; r < 4; r++)
                st[(quad * 4 + r) * S + nt * 16 + mr] = f2b(fmaxf(acc[nt][r] + bv, 0.0f));
        }
        unsigned short* op = (unsigned short*)out;
#pragma unroll
        for (int it = 0; it < 4; it++) {
            int linear = lane + it * 64;        // 256 ushort8-chunks: 16 rows x 16
            int row = linear >> 4, col = (linear & 15) << 3;
            int gm = m_base + row;
            if (gm < M) {
                uint4 val = *(uint4*)&st[row * S + col];
                *(uint4*)(op + (size_t)gm * D + col) = val;
            }
        }
    }
}

// ---------------- launch ----------------

extern "C" void kernel_launch(void* const* d_in, const int* in_sizes, int n_in,
                              void* d_out, int out_size, void* d_ws, size_t ws_size,
                              hipStream_t stream) {
    const float* x = (const float*)d_in[0];
    const int* ei = (const int*)d_in[1];
    const int* srcv = ei;
    const int* dstv = ei + N_EDGES;
    const float* W1[3] = {(const float*)d_in[2], (const float*)d_in[6], (const float*)d_in[10]};
    const float* b1[3] = {(const float*)d_in[3], (const float*)d_in[7], (const float*)d_in[11]};
    const float* W2[3] = {(const float*)d_in[4], (const float*)d_in[8], (const float*)d_in[12]};
    const float* b2[3] = {(const float*)d_in[5], (const float*)d_in[9], (const float*)d_in[13]};

    char* ws = (char*)d_ws;
    int* off = (int*)ws;                               // (N+1) ints
    int* cnt = (int*)(ws + 400128);                    // N ints (deg, cursor; dead after scatter)
    int* csr = (int*)(ws + 800256);                    // E ints (ends 7200256)
    unsigned short* xb = (unsigned short*)(ws + 7200256);   // N*D bf16 (25.6MB, ends 32800256)
    unsigned short* P  = (unsigned short*)(ws + 32800256);  // N*D bf16 (25.6MB, ends 58400256)
    // Wt overlays the dead cnt region after scatter completes
    unsigned short* Wt[6];
    for (int i = 0; i < 6; i++) Wt[i] = (unsigned short*)(ws + 400128 + i * 32768);

    // --- CSR build (once; reused by all 3 layers) ---
    hipMemsetAsync(cnt, 0, (size_t)N_NODES * 4, stream);
    hist_kernel<<<(N_EDGES + 255) / 256, 256, 0, stream>>>(dstv, cnt, N_EDGES);
    scan_kernel<<<1, 1024, 0, stream>>>(cnt, off, N_NODES);
    hipMemsetAsync(cnt, 0, (size_t)N_NODES * 4, stream);
    scatter_kernel<<<(N_EDGES + 255) / 256, 256, 0, stream>>>(srcv, dstv, off, cnt, csr, N_EDGES);

    // --- dtype conversions (cnt dead now) ---
    convert_w6_kernel<<<dim3(64, 6), 256, 0, stream>>>(
        W1[0], W2[0], W1[1], W2[1], W1[2], W2[2],
        Wt[0], Wt[1], Wt[2], Wt[3], Wt[4], Wt[5]);
    convert_x_kernel<<<(3200000 + 255) / 256, 256, 0, stream>>>(x, xb, 3200000);

    const int agg_grid = 25000;                        // 4 nodes/block
    const int gemm_grid = (N_NODES + 63) / 64;         // 1563

    // layer 0
    agg_bf16<<<agg_grid, 256, 0, stream>>>((const unsigned int*)xb, off, csr, (unsigned int*)P);
    gemm_mfma<false><<<gemm_grid, 256, 0, stream>>>(P, Wt[0], b1[0], xb, N_NODES);
    gemm_mfma<false><<<gemm_grid, 256, 0, stream>>>(xb, Wt[1], b2[0], P, N_NODES);
    // layer 1
    agg_bf16<<<agg_grid, 256, 0, stream>>>((const unsigned int*)P, off, csr, (unsigned int*)xb);
    gemm_mfma<false><<<gemm_grid, 256, 0, stream>>>(xb, Wt[2], b1[1], P, N_NODES);
    gemm_mfma<false><<<gemm_grid, 256, 0, stream>>>(P, Wt[3], b2[1], xb, N_NODES);
    // layer 2
    agg_bf16<<<agg_grid, 256, 0, stream>>>((const unsigned int*)xb, off, csr, (unsigned int*)P);
    gemm_mfma<false><<<gemm_grid, 256, 0, stream>>>(P, Wt[4], b1[2], xb, N_NODES);
    gemm_mfma<true><<<gemm_grid, 256, 0, stream>>>(xb, Wt[5], b2[2], d_out, N_NODES);
}

// Round 3
// 708.331 us; speedup vs baseline: 1.7720x; 1.1755x over previous
//
#include <hip/hip_runtime.h>

#define N_NODES 100000
#define N_EDGES 1600000
#define D 128
#define SCAN_BLOCKS 391   // ceil(N_NODES / 256)

typedef __attribute__((ext_vector_type(8))) short bf16x8;
typedef __attribute__((ext_vector_type(4))) float f32x4;

__device__ __forceinline__ float b2f_lo(unsigned int u) {
    return __builtin_bit_cast(float, u << 16);
}
__device__ __forceinline__ float b2f_hi(unsigned int u) {
    return __builtin_bit_cast(float, u & 0xFFFF0000u);
}
__device__ __forceinline__ unsigned short f2b(float f) {
    unsigned int u = __builtin_bit_cast(unsigned int, f);
    u += 0x7FFFu + ((u >> 16) & 1u);
    return (unsigned short)(u >> 16);
}

// ---------------- CSR build ----------------

__global__ void hist_kernel(const int* __restrict__ dst, int* __restrict__ deg, int n) {
    int i = blockIdx.x * blockDim.x + threadIdx.x;
    if (i < n) atomicAdd(&deg[dst[i]], 1);
}

// Hierarchical scan replacing the old single-block scan_kernel (was 161 us on 1 CU).
__global__ __launch_bounds__(256) void block_sum_kernel(const int* __restrict__ deg,
                                                        int* __restrict__ bsum) {
    __shared__ int s[256];
    int i = blockIdx.x * 256 + threadIdx.x;
    int v = (i < N_NODES) ? deg[i] : 0;
    s[threadIdx.x] = v;
    __syncthreads();
#pragma unroll
    for (int d = 128; d > 0; d >>= 1) {
        if (threadIdx.x < d) s[threadIdx.x] += s[threadIdx.x + d];
        __syncthreads();
    }
    if (threadIdx.x == 0) bsum[blockIdx.x] = s[0];
}

__global__ __launch_bounds__(512) void scan_bsum_kernel(const int* __restrict__ bsum,
                                                        int* __restrict__ bpref,
                                                        int* __restrict__ off) {
    __shared__ int s[512];
    int tid = threadIdx.x;
    int v = (tid < SCAN_BLOCKS) ? bsum[tid] : 0;
    s[tid] = v;
    __syncthreads();
#pragma unroll
    for (int d = 1; d < 512; d <<= 1) {
        int t = (tid >= d) ? s[tid - d] : 0;
        __syncthreads();
        s[tid] += t;
        __syncthreads();
    }
    if (tid < SCAN_BLOCKS) bpref[tid] = s[tid] - v;   // exclusive
    if (tid == 0) off[N_NODES] = N_EDGES;
}

__global__ __launch_bounds__(256) void block_scan_kernel(const int* __restrict__ deg,
                                                         const int* __restrict__ bpref,
                                                         int* __restrict__ off) {
    __shared__ int s[256];
    int i = blockIdx.x * 256 + threadIdx.x;
    int tid = threadIdx.x;
    int v = (i < N_NODES) ? deg[i] : 0;
    s[tid] = v;
    __syncthreads();
#pragma unroll
    for (int d = 1; d < 256; d <<= 1) {
        int t = (tid >= d) ? s[tid - d] : 0;
        __syncthreads();
        s[tid] += t;
        __syncthreads();
    }
    if (i < N_NODES) off[i] = bpref[blockIdx.x] + s[tid] - v;   // exclusive
}

__global__ void scatter_kernel(const int* __restrict__ srcv, const int* __restrict__ dstv,
                               const int* __restrict__ off, int* __restrict__ cnt,
                               int* __restrict__ csr, int n) {
    int i = blockIdx.x * blockDim.x + threadIdx.x;
    if (i < n) {
        int d = dstv[i];
        int p = off[d] + atomicAdd(&cnt[d], 1);
        csr[p] = srcv[i];
    }
}

// ---------------- dtype conversion ----------------

__global__ __launch_bounds__(256) void convert_x_kernel(const float* __restrict__ x,
                                                        unsigned short* __restrict__ xb, int n4) {
    int i = blockIdx.x * 256 + threadIdx.x;
    if (i < n4) {
        float4 v = ((const float4*)x)[i];
        ushort4 o;
        o.x = f2b(v.x); o.y = f2b(v.y); o.z = f2b(v.z); o.w = f2b(v.w);
        ((ushort4*)xb)[i] = o;
    }
}

__global__ __launch_bounds__(256) void convert_w6_kernel(
    const float* __restrict__ W0, const float* __restrict__ W1_, const float* __restrict__ W2_,
    const float* __restrict__ W3, const float* __restrict__ W4, const float* __restrict__ W5,
    unsigned short* __restrict__ T0, unsigned short* __restrict__ T1_,
    unsigned short* __restrict__ T2_, unsigned short* __restrict__ T3,
    unsigned short* __restrict__ T4, unsigned short* __restrict__ T5) {
    const float* W;
    unsigned short* T;
    switch (blockIdx.y) {
        case 0: W = W0; T = T0; break;
        case 1: W = W1_; T = T1_; break;
        case 2: W = W2_; T = T2_; break;
        case 3: W = W3; T = T3; break;
        case 4: W = W4; T = T4; break;
        default: W = W5; T = T5; break;
    }
    int i = blockIdx.x * 256 + threadIdx.x;   // 0..16383
    int k = i >> 7, n = i & 127;
    T[n * 128 + k] = f2b(W[i]);
}

// ---------------- aggregation: t[i] = x[i] + sum_{j in N_in(i)} x[j]  (bf16 in/out) ----------------

__global__ __launch_bounds__(256) void agg_bf16(const unsigned int* __restrict__ xb,
                                                const int* __restrict__ off,
                                                const int* __restrict__ csr,
                                                unsigned int* __restrict__ t) {
    int node = blockIdx.x * 4 + (threadIdx.x >> 6);
    if (node >= N_NODES) return;
    int lane = threadIdx.x & 63;
    unsigned int v = xb[(size_t)node * 64 + lane];
    float ax = b2f_lo(v), ay = b2f_hi(v);
    int e = off[node + 1];
    int k = off[node];
    for (; k + 4 <= e; k += 4) {
        int n0 = csr[k + 0], n1 = csr[k + 1], n2 = csr[k + 2], n3 = csr[k + 3];
        unsigned int g0 = xb[(size_t)n0 * 64 + lane];
        unsigned int g1 = xb[(size_t)n1 * 64 + lane];
        unsigned int g2 = xb[(size_t)n2 * 64 + lane];
        unsigned int g3 = xb[(size_t)n3 * 64 + lane];
        ax += b2f_lo(g0) + b2f_lo(g1) + b2f_lo(g2) + b2f_lo(g3);
        ay += b2f_hi(g0) + b2f_hi(g1) + b2f_hi(g2) + b2f_hi(g3);
    }
    for (; k < e; k++) {
        unsigned int g = xb[(size_t)csr[k] * 64 + lane];
        ax += b2f_lo(g);
        ay += b2f_hi(g);
    }
    t[(size_t)node * 64 + lane] = (unsigned int)f2b(ax) | ((unsigned int)f2b(ay) << 16);
}

// ---------------- GEMM: out = relu(A @ W + bias) via bf16 MFMA ----------------

template <bool OUT_F32>
__global__ __launch_bounds__(256) void gemm_mfma(const unsigned short* __restrict__ A,
                                                 const unsigned short* __restrict__ Wt,
                                                 const float* __restrict__ bias,
                                                 void* __restrict__ out, int M) {
    __shared__ char smem[4][8448];  // per-wave staging: 16 rows x (132 f32 | 136 bf16)
    int tid = threadIdx.x;
    int wave = tid >> 6, lane = tid & 63;
    int quad = lane >> 4, mr = lane & 15;
    int m_base = blockIdx.x * 64 + wave * 16;
    int m = m_base + mr;
    if (m >= M) m = M - 1;

    bf16x8 a[4];
#pragma unroll
    for (int kc = 0; kc < 4; kc++)
        a[kc] = *(const bf16x8*)(A + (size_t)m * D + kc * 32 + quad * 8);

    f32x4 acc[8];
#pragma unroll
    for (int nt = 0; nt < 8; nt++) acc[nt] = (f32x4)0.0f;

#pragma unroll
    for (int nt = 0; nt < 8; nt++) {
        const unsigned short* wp = Wt + (size_t)(nt * 16 + mr) * D + quad * 8;
#pragma unroll
        for (int kc = 0; kc < 4; kc++) {
            bf16x8 b = *(const bf16x8*)(wp + kc * 32);
            acc[nt] = __builtin_amdgcn_mfma_f32_16x16x32_bf16(a[kc], b, acc[nt], 0, 0, 0);
        }
    }

    // D layout: col = lane&15 (=mr), row = quad*4 + reg
    if (OUT_F32) {
        float* st = (float*)smem[wave];
        const int S = 132;
#pragma unroll
        for (int nt = 0; nt < 8; nt++) {
            float bv = bias[nt * 16 + mr];
#pragma unroll
            for (int r = 0; r < 4; r++)
                st[(quad * 4 + r) * S + nt * 16 + mr] = fmaxf(acc[nt][r] + bv, 0.0f);
        }
        float* op = (float*)out;
#pragma unroll
        for (int it = 0; it < 8; it++) {
            int linear = lane + it * 64;
            int row = linear >> 5, col = (linear & 31) << 2;
            int gm = m_base + row;
            if (gm < M) {
                float4 val = *(float4*)&st[row * S + col];
                *(float4*)(op + (size_t)gm * D + col) = val;
            }
        }
    } else {
        unsigned short* st = (unsigned short*)smem[wave];
        const int S = 136;
#pragma unroll
        for (int nt = 0; nt < 8; nt++) {
            float bv = bias[nt * 16 + mr];
#pragma unroll
            for (int r = 0; r < 4; r++)
                st[(quad * 4 + r) * S + nt * 16 + mr] = f2b(fmaxf(acc[nt][r] + bv, 0.0f));
        }
        unsigned short* op = (unsigned short*)out;
#pragma unroll
        for (int it = 0; it < 4; it++) {
            int linear = lane + it * 64;
            int row = linear >> 4, col = (linear & 15) << 3;
            int gm = m_base + row;
            if (gm < M) {
                uint4 val = *(uint4*)&st[row * S + col];
                *(uint4*)(op + (size_t)gm * D + col) = val;
            }
        }
    }
}

// ---------------- launch ----------------

extern "C" void kernel_launch(void* const* d_in, const int* in_sizes, int n_in,
                              void* d_out, int out_size, void* d_ws, size_t ws_size,
                              hipStream_t stream) {
    const float* x = (const float*)d_in[0];
    const int* ei = (const int*)d_in[1];
    const int* srcv = ei;
    const int* dstv = ei + N_EDGES;
    const float* W1[3] = {(const float*)d_in[2], (const float*)d_in[6], (const float*)d_in[10]};
    const float* b1[3] = {(const float*)d_in[3], (const float*)d_in[7], (const float*)d_in[11]};
    const float* W2[3] = {(const float*)d_in[4], (const float*)d_in[8], (const float*)d_in[12]};
    const float* b2[3] = {(const float*)d_in[5], (const float*)d_in[9], (const float*)d_in[13]};

    char* ws = (char*)d_ws;
    int* off = (int*)ws;                               // (N+1) ints
    int* cnt = (int*)(ws + 400128);                    // N ints (deg, cursor; dead after scatter)
    int* csr = (int*)(ws + 800256);                    // E ints (ends 7200256)
    unsigned short* xb = (unsigned short*)(ws + 7200256);   // N*D bf16 (ends 32800256)
    unsigned short* P  = (unsigned short*)(ws + 32800256);  // N*D bf16 (ends 58400256)
    // bsum/bpref live in the front of the xb region (dead before convert_x runs)
    int* bsum  = (int*)(ws + 7200256);
    int* bpref = (int*)(ws + 7200256 + 2048);
    // Wt overlays the dead cnt region after scatter completes
    unsigned short* Wt[6];
    for (int i = 0; i < 6; i++) Wt[i] = (unsigned short*)(ws + 400128 + i * 32768);

    // --- CSR build (once; reused by all 3 layers) ---
    hipMemsetAsync(cnt, 0, (size_t)N_NODES * 4, stream);
    hist_kernel<<<(N_EDGES + 255) / 256, 256, 0, stream>>>(dstv, cnt, N_EDGES);
    block_sum_kernel<<<SCAN_BLOCKS, 256, 0, stream>>>(cnt, bsum);
    scan_bsum_kernel<<<1, 512, 0, stream>>>(bsum, bpref, off);
    block_scan_kernel<<<SCAN_BLOCKS, 256, 0, stream>>>(cnt, bpref, off);
    hipMemsetAsync(cnt, 0, (size_t)N_NODES * 4, stream);
    scatter_kernel<<<(N_EDGES + 255) / 256, 256, 0, stream>>>(srcv, dstv, off, cnt, csr, N_EDGES);

    // --- dtype conversions (cnt + bsum/bpref dead now) ---
    convert_w6_kernel<<<dim3(64, 6), 256, 0, stream>>>(
        W1[0], W2[0], W1[1], W2[1], W1[2], W2[2],
        Wt[0], Wt[1], Wt[2], Wt[3], Wt[4], Wt[5]);
    convert_x_kernel<<<(3200000 + 255) / 256, 256, 0, stream>>>(x, xb, 3200000);

    const int agg_grid = 25000;                        // 4 nodes/block
    const int gemm_grid = (N_NODES + 63) / 64;         // 1563

    // layer 0
    agg_bf16<<<agg_grid, 256, 0, stream>>>((const unsigned int*)xb, off, csr, (unsigned int*)P);
    gemm_mfma<false><<<gemm_grid, 256, 0, stream>>>(P, Wt[0], b1[0], xb, N_NODES);
    gemm_mfma<false><<<gemm_grid, 256, 0, stream>>>(xb, Wt[1], b2[0], P, N_NODES);
    // layer 1
    agg_bf16<<<agg_grid, 256, 0, stream>>>((const unsigned int*)P, off, csr, (unsigned int*)xb);
    gemm_mfma<false><<<gemm_grid, 256, 0, stream>>>(xb, Wt[2], b1[1], P, N_NODES);
    gemm_mfma<false><<<gemm_grid, 256, 0, stream>>>(P, Wt[3], b2[1], xb, N_NODES);
    // layer 2
    agg_bf16<<<agg_grid, 256, 0, stream>>>((const unsigned int*)xb, off, csr, (unsigned int*)P);
    gemm_mfma<false><<<gemm_grid, 256, 0, stream>>>(P, Wt[4], b1[2], xb, N_NODES);
    gemm_mfma<true><<<gemm_grid, 256, 0, stream>>>(xb, Wt[5], b2[2], d_out, N_NODES);
}

// Round 4
// 680.564 us; speedup vs baseline: 1.8443x; 1.0408x over previous
//
#include <hip/hip_runtime.h>

#define N_NODES 100000
#define N_EDGES 1600000
#define D 128
#define SCAN_BLOCKS 391   // ceil(N_NODES / 256)
#define NBUCK 782         // ceil(N_NODES / 128), bucket = dst >> 7

typedef __attribute__((ext_vector_type(8))) short bf16x8;
typedef __attribute__((ext_vector_type(4))) float f32x4;

__device__ __forceinline__ float b2f_lo(unsigned int u) {
    return __builtin_bit_cast(float, u << 16);
}
__device__ __forceinline__ float b2f_hi(unsigned int u) {
    return __builtin_bit_cast(float, u & 0xFFFF0000u);
}
__device__ __forceinline__ unsigned short f2b(float f) {
    unsigned int u = __builtin_bit_cast(unsigned int, f);
    u += 0x7FFFu + ((u >> 16) & 1u);
    return (unsigned short)(u >> 16);
}

// ---------------- CSR build: bucketed counting sort by dst ----------------
// Old single-pass scatter had 16x write amplification (107MB WRITE_SIZE for 6.4MB of
// csr). Bucketing by dst>>7 makes both the bin writes and the final scatter writes
// L2-resident sequential slabs -> amplification ~1.

__global__ __launch_bounds__(256) void bucket_hist_kernel(const int* __restrict__ dst,
                                                          int* __restrict__ bcnt) {
    __shared__ int h[NBUCK];
    for (int i = threadIdx.x; i < NBUCK; i += 256) h[i] = 0;
    __syncthreads();
    int e0 = blockIdx.x * 4096;
#pragma unroll
    for (int i = 0; i < 16; i++) {
        int e = e0 + threadIdx.x + i * 256;
        if (e < N_EDGES) atomicAdd(&h[dst[e] >> 7], 1);
    }
    __syncthreads();
    for (int i = threadIdx.x; i < NBUCK; i += 256)
        if (h[i]) atomicAdd(&bcnt[i], h[i]);
}

__global__ __launch_bounds__(1024) void bucket_scan_kernel(const int* __restrict__ bcnt,
                                                           int* __restrict__ boff) {
    __shared__ int s[1024];
    int tid = threadIdx.x;
    int v = (tid < NBUCK) ? bcnt[tid] : 0;
    s[tid] = v;
    __syncthreads();
#pragma unroll
    for (int d = 1; d < 1024; d <<= 1) {
        int t = (tid >= d) ? s[tid - d] : 0;
        __syncthreads();
        s[tid] += t;
        __syncthreads();
    }
    if (tid < NBUCK) boff[tid] = s[tid] - v;   // exclusive
}

// Bin edges into bucket-ordered (src,dst) arrays; also build node-degree histogram.
__global__ __launch_bounds__(256) void bin_kernel(const int* __restrict__ src,
                                                  const int* __restrict__ dst,
                                                  const int* __restrict__ boff,
                                                  int* __restrict__ bcur,
                                                  int* __restrict__ deg,
                                                  int* __restrict__ sbuf,
                                                  int* __restrict__ dbuf) {
    __shared__ int h[NBUCK];
    __shared__ int base[NBUCK];
    int tid = threadIdx.x;
    for (int i = tid; i < NBUCK; i += 256) h[i] = 0;
    __syncthreads();
    int e0 = blockIdx.x * 4096;
    int myd[16], mys[16];
#pragma unroll
    for (int i = 0; i < 16; i++) {
        int e = e0 + tid + i * 256;
        int dv = (e < N_EDGES) ? dst[e] : -1;
        myd[i] = dv;
        mys[i] = (e < N_EDGES) ? src[e] : 0;
        if (dv >= 0) {
            atomicAdd(&h[dv >> 7], 1);
            atomicAdd(&deg[dv], 1);
        }
    }
    __syncthreads();
    for (int i = tid; i < NBUCK; i += 256) {
        int c = h[i];
        base[i] = (c > 0) ? (boff[i] + atomicAdd(&bcur[i], c)) : 0;
        h[i] = 0;
    }
    __syncthreads();
#pragma unroll
    for (int i = 0; i < 16; i++) {
        int dv = myd[i];
        if (dv >= 0) {
            int b = dv >> 7;
            int p = base[b] + atomicAdd(&h[b], 1);
            sbuf[p] = mys[i];
            dbuf[p] = dv;
        }
    }
}

__global__ __launch_bounds__(256) void scatter2_kernel(const int* __restrict__ sbuf,
                                                       const int* __restrict__ dbuf,
                                                       const int* __restrict__ off,
                                                       int* __restrict__ cnt,
                                                       int* __restrict__ csr) {
    int i = blockIdx.x * 256 + threadIdx.x;
    if (i < N_EDGES) {
        int dv = dbuf[i];
        int p = off[dv] + atomicAdd(&cnt[dv], 1);
        csr[p] = sbuf[i];   // bucket-ordered input -> writes land in an ~8KB csr window
    }
}

// ---------------- hierarchical node-degree scan ----------------

__global__ __launch_bounds__(256) void block_sum_kernel(const int* __restrict__ deg,
                                                        int* __restrict__ bsum) {
    __shared__ int s[256];
    int i = blockIdx.x * 256 + threadIdx.x;
    int v = (i < N_NODES) ? deg[i] : 0;
    s[threadIdx.x] = v;
    __syncthreads();
#pragma unroll
    for (int d = 128; d > 0; d >>= 1) {
        if (threadIdx.x < d) s[threadIdx.x] += s[threadIdx.x + d];
        __syncthreads();
    }
    if (threadIdx.x == 0) bsum[blockIdx.x] = s[0];
}

__global__ __launch_bounds__(512) void scan_bsum_kernel(const int* __restrict__ bsum,
                                                        int* __restrict__ bpref,
                                                        int* __restrict__ off) {
    __shared__ int s[512];
    int tid = threadIdx.x;
    int v = (tid < SCAN_BLOCKS) ? bsum[tid] : 0;
    s[tid] = v;
    __syncthreads();
#pragma unroll
    for (int d = 1; d < 512; d <<= 1) {
        int t = (tid >= d) ? s[tid - d] : 0;
        __syncthreads();
        s[tid] += t;
        __syncthreads();
    }
    if (tid < SCAN_BLOCKS) bpref[tid] = s[tid] - v;   // exclusive
    if (tid == 0) off[N_NODES] = N_EDGES;
}

__global__ __launch_bounds__(256) void block_scan_kernel(const int* __restrict__ deg,
                                                         const int* __restrict__ bpref,
                                                         int* __restrict__ off) {
    __shared__ int s[256];
    int i = blockIdx.x * 256 + threadIdx.x;
    int tid = threadIdx.x;
    int v = (i < N_NODES) ? deg[i] : 0;
    s[tid] = v;
    __syncthreads();
#pragma unroll
    for (int d = 1; d < 256; d <<= 1) {
        int t = (tid >= d) ? s[tid - d] : 0;
        __syncthreads();
        s[tid] += t;
        __syncthreads();
    }
    if (i < N_NODES) off[i] = bpref[blockIdx.x] + s[tid] - v;   // exclusive
}

// ---------------- dtype conversion ----------------

__global__ __launch_bounds__(256) void convert_x_kernel(const float* __restrict__ x,
                                                        unsigned short* __restrict__ xb, int n4) {
    int i = blockIdx.x * 256 + threadIdx.x;
    if (i < n4) {
        float4 v = ((const float4*)x)[i];
        ushort4 o;
        o.x = f2b(v.x); o.y = f2b(v.y); o.z = f2b(v.z); o.w = f2b(v.w);
        ((ushort4*)xb)[i] = o;
    }
}

__global__ __launch_bounds__(256) void convert_w6_kernel(
    const float* __restrict__ W0, const float* __restrict__ W1_, const float* __restrict__ W2_,
    const float* __restrict__ W3, const float* __restrict__ W4, const float* __restrict__ W5,
    unsigned short* __restrict__ T0, unsigned short* __restrict__ T1_,
    unsigned short* __restrict__ T2_, unsigned short* __restrict__ T3,
    unsigned short* __restrict__ T4, unsigned short* __restrict__ T5) {
    const float* W;
    unsigned short* T;
    switch (blockIdx.y) {
        case 0: W = W0; T = T0; break;
        case 1: W = W1_; T = T1_; break;
        case 2: W = W2_; T = T2_; break;
        case 3: W = W3; T = T3; break;
        case 4: W = W4; T = T4; break;
        default: W = W5; T = T5; break;
    }
    int i = blockIdx.x * 256 + threadIdx.x;   // 0..16383
    int k = i >> 7, n = i & 127;
    T[n * 128 + k] = f2b(W[i]);
}

// ---------------- aggregation: t[i] = x[i] + sum_{j in N_in(i)} x[j]  (bf16 in/out) ----------------

__global__ __launch_bounds__(256) void agg_bf16(const unsigned int* __restrict__ xb,
                                                const int* __restrict__ off,
                                                const int* __restrict__ csr,
                                                unsigned int* __restrict__ t) {
    int node = blockIdx.x * 4 + (threadIdx.x >> 6);
    if (node >= N_NODES) return;
    int lane = threadIdx.x & 63;
    unsigned int v = xb[(size_t)node * 64 + lane];
    float ax = b2f_lo(v), ay = b2f_hi(v);
    int e = off[node + 1];
    int k = off[node];
    for (; k + 4 <= e; k += 4) {
        int n0 = csr[k + 0], n1 = csr[k + 1], n2 = csr[k + 2], n3 = csr[k + 3];
        unsigned int g0 = xb[(size_t)n0 * 64 + lane];
        unsigned int g1 = xb[(size_t)n1 * 64 + lane];
        unsigned int g2 = xb[(size_t)n2 * 64 + lane];
        unsigned int g3 = xb[(size_t)n3 * 64 + lane];
        ax += b2f_lo(g0) + b2f_lo(g1) + b2f_lo(g2) + b2f_lo(g3);
        ay += b2f_hi(g0) + b2f_hi(g1) + b2f_hi(g2) + b2f_hi(g3);
    }
    for (; k < e; k++) {
        unsigned int g = xb[(size_t)csr[k] * 64 + lane];
        ax += b2f_lo(g);
        ay += b2f_hi(g);
    }
    t[(size_t)node * 64 + lane] = (unsigned int)f2b(ax) | ((unsigned int)f2b(ay) << 16);
}

// ---------------- GEMM: out = relu(A @ W + bias) via bf16 MFMA ----------------

template <bool OUT_F32>
__global__ __launch_bounds__(256) void gemm_mfma(const unsigned short* __restrict__ A,
                                                 const unsigned short* __restrict__ Wt,
                                                 const float* __restrict__ bias,
                                                 void* __restrict__ out, int M) {
    __shared__ char smem[4][8448];  // per-wave staging: 16 rows x (132 f32 | 136 bf16)
    int tid = threadIdx.x;
    int wave = tid >> 6, lane = tid & 63;
    int quad = lane >> 4, mr = lane & 15;
    int m_base = blockIdx.x * 64 + wave * 16;
    int m = m_base + mr;
    if (m >= M) m = M - 1;

    bf16x8 a[4];
#pragma unroll
    for (int kc = 0; kc < 4; kc++)
        a[kc] = *(const bf16x8*)(A + (size_t)m * D + kc * 32 + quad * 8);

    f32x4 acc[8];
#pragma unroll
    for (int nt = 0; nt < 8; nt++) acc[nt] = (f32x4)0.0f;

#pragma unroll
    for (int nt = 0; nt < 8; nt++) {
        const unsigned short* wp = Wt + (size_t)(nt * 16 + mr) * D + quad * 8;
#pragma unroll
        for (int kc = 0; kc < 4; kc++) {
            bf16x8 b = *(const bf16x8*)(wp + kc * 32);
            acc[nt] = __builtin_amdgcn_mfma_f32_16x16x32_bf16(a[kc], b, acc[nt], 0, 0, 0);
        }
    }

    // D layout: col = lane&15 (=mr), row = quad*4 + reg
    if (OUT_F32) {
        float* st = (float*)smem[wave];
        const int S = 132;
#pragma unroll
        for (int nt = 0; nt < 8; nt++) {
            float bv = bias[nt * 16 + mr];
#pragma unroll
            for (int r = 0; r < 4; r++)
                st[(quad * 4 + r) * S + nt * 16 + mr] = fmaxf(acc[nt][r] + bv, 0.0f);
        }
        float* op = (float*)out;
#pragma unroll
        for (int it = 0; it < 8; it++) {
            int linear = lane + it * 64;
            int row = linear >> 5, col = (linear & 31) << 2;
            int gm = m_base + row;
            if (gm < M) {
                float4 val = *(float4*)&st[row * S + col];
                *(float4*)(op + (size_t)gm * D + col) = val;
            }
        }
    } else {
        unsigned short* st = (unsigned short*)smem[wave];
        const int S = 136;
#pragma unroll
        for (int nt = 0; nt < 8; nt++) {
            float bv = bias[nt * 16 + mr];
#pragma unroll
            for (int r = 0; r < 4; r++)
                st[(quad * 4 + r) * S + nt * 16 + mr] = f2b(fmaxf(acc[nt][r] + bv, 0.0f));
        }
        unsigned short* op = (unsigned short*)out;
#pragma unroll
        for (int it = 0; it < 4; it++) {
            int linear = lane + it * 64;
            int row = linear >> 4, col = (linear & 15) << 3;
            int gm = m_base + row;
            if (gm < M) {
                uint4 val = *(uint4*)&st[row * S + col];
                *(uint4*)(op + (size_t)gm * D + col) = val;
            }
        }
    }
}

// ---------------- launch ----------------

extern "C" void kernel_launch(void* const* d_in, const int* in_sizes, int n_in,
                              void* d_out, int out_size, void* d_ws, size_t ws_size,
                              hipStream_t stream) {
    const float* x = (const float*)d_in[0];
    const int* ei = (const int*)d_in[1];
    const int* srcv = ei;
    const int* dstv = ei + N_EDGES;
    const float* W1[3] = {(const float*)d_in[2], (const float*)d_in[6], (const float*)d_in[10]};
    const float* b1[3] = {(const float*)d_in[3], (const float*)d_in[7], (const float*)d_in[11]};
    const float* W2[3] = {(const float*)d_in[4], (const float*)d_in[8], (const float*)d_in[12]};
    const float* b2[3] = {(const float*)d_in[5], (const float*)d_in[9], (const float*)d_in[13]};

    char* ws = (char*)d_ws;
    int* off = (int*)ws;                               // (N+1) ints
    int* deg = (int*)(ws + 400128);                    // N ints (degree, then scatter cursor)
    int* csr = (int*)(ws + 800256);                    // E ints (ends 7200256)
    unsigned short* xb = (unsigned short*)(ws + 7200256);   // N*D bf16 (ends 32800256)
    unsigned short* P  = (unsigned short*)(ws + 32800256);  // N*D bf16 (ends 58400256)
    // bucket-sorted edge arrays overlay xb/P (dead until converts run)
    int* sbuf = (int*)(ws + 7200256);                  // E ints
    int* dbuf = (int*)(ws + 32800256);                 // E ints
    // small counters live in the front of d_out (fully overwritten by the final GEMM)
    char* dob = (char*)d_out;
    int* bcnt  = (int*)(dob + 0);
    int* boff  = (int*)(dob + 4096);
    int* bcur  = (int*)(dob + 8192);
    int* bsum  = (int*)(dob + 12288);
    int* bpref = (int*)(dob + 16384);
    // Wt overlays the dead deg region after scatter2 completes
    unsigned short* Wt[6];
    for (int i = 0; i < 6; i++) Wt[i] = (unsigned short*)(ws + 400128 + i * 32768);

    // --- CSR build (bucketed counting sort; reused by all 3 layers) ---
    hipMemsetAsync(dob, 0, 20480, stream);
    hipMemsetAsync(deg, 0, (size_t)N_NODES * 4, stream);
    bucket_hist_kernel<<<391, 256, 0, stream>>>(dstv, bcnt);
    bucket_scan_kernel<<<1, 1024, 0, stream>>>(bcnt, boff);
    bin_kernel<<<391, 256, 0, stream>>>(srcv, dstv, boff, bcur, deg, sbuf, dbuf);
    block_sum_kernel<<<SCAN_BLOCKS, 256, 0, stream>>>(deg, bsum);
    scan_bsum_kernel<<<1, 512, 0, stream>>>(bsum, bpref, off);
    block_scan_kernel<<<SCAN_BLOCKS, 256, 0, stream>>>(deg, bpref, off);
    hipMemsetAsync(deg, 0, (size_t)N_NODES * 4, stream);
    scatter2_kernel<<<(N_EDGES + 255) / 256, 256, 0, stream>>>(sbuf, dbuf, off, deg, csr);

    // --- dtype conversions (deg + sbuf/dbuf dead now) ---
    convert_w6_kernel<<<dim3(64, 6), 256, 0, stream>>>(
        W1[0], W2[0], W1[1], W2[1], W1[2], W2[2],
        Wt[0], Wt[1], Wt[2], Wt[3], Wt[4], Wt[5]);
    convert_x_kernel<<<(3200000 + 255) / 256, 256, 0, stream>>>(x, xb, 3200000);

    const int agg_grid = 25000;                        // 4 nodes/block
    const int gemm_grid = (N_NODES + 63) / 64;         // 1563

    // layer 0
    agg_bf16<<<agg_grid, 256, 0, stream>>>((const unsigned int*)xb, off, csr, (unsigned int*)P);
    gemm_mfma<false><<<gemm_grid, 256, 0, stream>>>(P, Wt[0], b1[0], xb, N_NODES);
    gemm_mfma<false><<<gemm_grid, 256, 0, stream>>>(xb, Wt[1], b2[0], P, N_NODES);
    // layer 1
    agg_bf16<<<agg_grid, 256, 0, stream>>>((const unsigned int*)P, off, csr, (unsigned int*)xb);
    gemm_mfma<false><<<gemm_grid, 256, 0, stream>>>(xb, Wt[2], b1[1], P, N_NODES);
    gemm_mfma<false><<<gemm_grid, 256, 0, stream>>>(P, Wt[3], b2[1], xb, N_NODES);
    // layer 2
    agg_bf16<<<agg_grid, 256, 0, stream>>>((const unsigned int*)xb, off, csr, (unsigned int*)P);
    gemm_mfma<false><<<gemm_grid, 256, 0, stream>>>(P, Wt[4], b1[2], xb, N_NODES);
    gemm_mfma<true><<<gemm_grid, 256, 0, stream>>>(xb, Wt[5], b2[2], d_out, N_NODES);
}